// Round 15
// baseline (1471.988 us; speedup 1.0000x reference)
//
#include <hip/hip_runtime.h>
#include <hip/hip_bf16.h>

#define N_PTS  65536
#define DMODEL 256
#define MSAMP  1024

#define NW    64   // FPS waves = single-wave workgroups (all co-resident)
#define FPT   16   // points per lane: 65536 / (64 * 64)
#define SLW   16   // u64s per slot line: 128B stride, one wave per line
#define NCAND 8    // candidates published per wave (+1 bound slot) — R10 proven
#define KMAX  16   // max emissions stashed per round (cap -> extra round, exact)

typedef short bf16x8_t __attribute__((ext_vector_type(8)));
typedef float f32x4_t  __attribute__((ext_vector_type(4)));

__device__ __forceinline__ short f2bs(float f) {
    __hip_bfloat16 h = __float2bfloat16(f);   // RNE
    return *reinterpret_cast<short*>(&h);
}

__device__ __forceinline__ bf16x8_t cvt8(const float* p) {
    f32x4_t a = *(const f32x4_t*)(p);
    f32x4_t b = *(const f32x4_t*)(p + 4);
    bf16x8_t r;
#pragma unroll
    for (int i = 0; i < 4; i++) { r[i] = f2bs(a[i]); r[i + 4] = f2bs(b[i]); }
    return r;
}

// exact numpy distance: per-op RN f32, ((dx^2+dy^2)+dz^2), no FMA
__device__ __forceinline__ float dist2(float ax, float ay, float az,
                                       float bx, float by, float bz) {
    float dx = __fsub_rn(ax, bx), dy = __fsub_rn(ay, by), dz = __fsub_rn(az, bz);
    return __fadd_rn(__fadd_rn(__fmul_rn(dx, dx), __fmul_rn(dy, dy)),
                     __fmul_rn(dz, dz));
}
// u64 max via f64 fmax (packs are positive f64 bit patterns; proven R5-R14)
__device__ __forceinline__ unsigned long long dmax64(unsigned long long a,
                                                     unsigned long long b) {
    double r = fmax(__longlong_as_double((long long)a),
                    __longlong_as_double((long long)b));
    return (unsigned long long)__double_as_longlong(r);
}
__device__ __forceinline__ unsigned long long bfly_max(unsigned long long v) {
    double dp = __longlong_as_double((long long)v);
#pragma unroll
    for (int s = 1; s < 64; s <<= 1)
        dp = fmax(dp, __shfl_xor(dp, s, 64));
    return (unsigned long long)__double_as_longlong(dp);
}

// ---------------------------------------------------------------------------
// Batched-candidate FPS, NCAND=8 (R10 skeleton). R15 change: dd-updates are
// DEFERRED out of the serial emission chain (R9-proven pattern). The emission
// loop updates only the 8 in-flight candidates (the values that feed the next
// argmax); winner coords are stashed in static-indexed register arrays and
// applied to the 16 local points in one pipelined batch at the start of the
// next round. Per-point min order == emission order -> bitwise-identical to
// R10/numpy. If a round's emissions would exceed KMAX we break (extra round,
// still exact). Liveness class unchanged (R10's proven publish/poll).
// ---------------------------------------------------------------------------
__global__ __launch_bounds__(64) void fps_kernel(
    const float*        __restrict__ xyz,      // (N,3) f32
    unsigned long long* __restrict__ slots,    // [2][NW][SLW] u64, zeroed per call
    int*                __restrict__ idx)      // (MSAMP) out
{
    const int l = threadIdx.x;       // 0..63
    const int g = blockIdx.x;        // 0..63
    const int base = g * (FPT * 64) + l;

    float px[FPT], py[FPT], pz[FPT], dd[FPT];
    unsigned long long ivi[FPT];
    const float c0x = xyz[0], c0y = xyz[1], c0z = xyz[2];   // winner 0 = point 0
#pragma unroll
    for (int i = 0; i < FPT; i++) {
        int p = base + i * 64;
        px[i] = xyz[3 * p + 0];
        py[i] = xyz[3 * p + 1];
        pz[i] = xyz[3 * p + 2];
        dd[i] = fminf(1e10f, dist2(px[i], py[i], pz[i], c0x, c0y, c0z));
        ivi[i] = (unsigned long long)(0xFFFFu - (unsigned)p);
    }
    if (g == 0 && l == 0) idx[0] = 0;

    float wxl[KMAX], wyl[KMAX], wzl[KMAX];
    int k = 0;                       // pending winners from previous round
    int total = 0, r = 0;
    while (total < MSAMP - 1) {
        ++r;
        // ---- 0) apply pending winners to dd (pipelined batch, exact order) --
#pragma unroll
        for (int t = 0; t < KMAX; t++) if (t < k) {
#pragma unroll
            for (int i = 0; i < FPT; i++)
                dd[i] = fminf(dd[i], dist2(px[i], py[i], pz[i],
                                           wxl[t], wyl[t], wzl[t]));
        }

        // ---- 1) extract top-(NCAND+1) packs ------------------------------
        unsigned long long pk[FPT];
#pragma unroll
        for (int i = 0; i < FPT; i++)
            pk[i] = (((unsigned long long)__float_as_uint(dd[i])) << 32) | ivi[i];

        unsigned long long top[NCAND + 1];
        unsigned long long prev = ~0ull;            // matches no pack
#pragma unroll
        for (int t = 0; t < NCAND + 1; t++) {
            unsigned long long lm = 0;
#pragma unroll
            for (int i = 0; i < FPT; i++) {
                pk[i] = (pk[i] == prev) ? 0ull : pk[i];
                lm = dmax64(lm, pk[i]);
            }
            unsigned long long gt = bfly_max(lm);
            top[t] = gt;
            prev = gt;
        }

        // ---- 2) publish (lanes 0..NCAND) + poll --------------------------
        const int ph = r & 1;
        const unsigned rt = (unsigned)(r & 0xFFFF);
        unsigned long long sv = top[0];
#pragma unroll
        for (int t = 1; t <= NCAND; t++) sv = (l == t) ? top[t] : sv;
        sv |= ((unsigned long long)rt) << 16;       // bits 16-31 free in packs
        if (l <= NCAND)
            __hip_atomic_store(slots + ((size_t)(ph * NW + g) * SLW + l), sv,
                               __ATOMIC_RELAXED, __HIP_MEMORY_SCOPE_AGENT);

        const unsigned long long* Q = slots + (size_t)ph * NW * SLW + (size_t)l * SLW;
        unsigned long long u[NCAND + 1];
        for (;;) {
            bool ok = true;
#pragma unroll
            for (int t = 0; t <= NCAND; t++) {
                u[t] = __hip_atomic_load(Q + t, __ATOMIC_RELAXED,
                                         __HIP_MEMORY_SCOPE_AGENT);
                ok &= (((unsigned)(u[t] >> 16) & 0xFFFFu) == rt);
            }
            if (__all(ok)) break;
            __builtin_amdgcn_s_sleep(2);
        }

        // ---- parse: lane l holds wave l's 8 candidates + bound -----------
        float cv[NCAND], cxc[NCAND], cyc[NCAND], czc[NCAND];
        unsigned ici[NCAND];
#pragma unroll
        for (int c = 0; c < NCAND; c++) {
            cv[c]  = __uint_as_float((unsigned)(u[c] >> 32));
            ici[c] = (unsigned)(u[c] & 0xFFFFu);
            int pi = 0xFFFF - (int)ici[c];
            cxc[c] = xyz[3 * pi + 0];
            cyc[c] = xyz[3 * pi + 1];
            czc[c] = xyz[3 * pi + 2];
        }
        float mB = __uint_as_float((unsigned)(u[NCAND] >> 32));
#pragma unroll
        for (int s = 1; s < 64; s <<= 1)
            mB = fmaxf(mB, __shfl_xor(mB, s, 64));

        // ---- 3) emission loop: candidate-updates ONLY in the chain -------
        int kk = 0;
        while (total < MSAMP - 1 && kk < KMAX) {
            unsigned long long lb = 0;
#pragma unroll
            for (int c = 0; c < NCAND; c++)
                lb = dmax64(lb, (((unsigned long long)__float_as_uint(cv[c])) << 32) | ici[c]);
            unsigned long long gb = bfly_max(lb);
            float gv = __uint_as_float((unsigned)(gb >> 32));
            if (kk > 0 && !(gv > mB)) break;     // strict >: exact vs unpublished

            int widx = 0xFFFF - (int)(gb & 0xFFFFu);
            if (g == 0 && l == 0) idx[total + 1] = widx;

            // winner coords from the owning lane (packs globally unique)
            float sx = cxc[0], sy = cyc[0], sz = czc[0];
#pragma unroll
            for (int c = 1; c < NCAND; c++) {
                bool h = ((((unsigned long long)__float_as_uint(cv[c])) << 32) | ici[c]) == gb;
                sx = h ? cxc[c] : sx;
                sy = h ? cyc[c] : sy;
                sz = h ? czc[c] : sz;
            }
            unsigned long long mo = __ballot(lb == gb);
            int ol = __ffsll((unsigned long long)mo) - 1;
            float wx = __shfl(sx, ol, 64);
            float wy = __shfl(sy, ol, 64);
            float wz = __shfl(sz, ol, 64);

            // stash winner (static-indexed register write)
#pragma unroll
            for (int t = 0; t < KMAX; t++) if (t == kk) { wxl[t] = wx; wyl[t] = wy; wzl[t] = wz; }

            // in-chain: candidates only (these feed the next argmax)
#pragma unroll
            for (int c = 0; c < NCAND; c++)
                cv[c] = fminf(cv[c], dist2(cxc[c], cyc[c], czc[c], wx, wy, wz));

            total++; kk++;
        }
        k = kk;
    }
}

// ---------------------------------------------------------------------------
// Gather + K/V projection in f32; outputs bf16. k pre-scaled by 1/16 (exact),
// row-major (j,k); v stored transposed (d,j).   [R10 verbatim, proven]
// ---------------------------------------------------------------------------
__global__ __launch_bounds__(256) void kv_kernel(
    const float* __restrict__ feat,
    const float* __restrict__ Wk, const float* __restrict__ bk,
    const float* __restrict__ Wv, const float* __restrict__ bv,
    const int* __restrict__ idx,
    unsigned short* __restrict__ k_s,   // (MSAMP, DMODEL) bf16, * 1/16
    unsigned short* __restrict__ vT)    // (DMODEL, MSAMP) bf16
{
    __shared__ float fl[4][DMODEL];
    const int t  = threadIdx.x;
    const int j0 = blockIdx.x * 4;
    {
        int jj = t >> 6;
        int e  = (t & 63) * 4;
        int src = idx[j0 + jj];
        f32x4_t v = *(const f32x4_t*)(feat + (size_t)src * DMODEL + e);
        fl[jj][e + 0] = v[0];
        fl[jj][e + 1] = v[1];
        fl[jj][e + 2] = v[2];
        fl[jj][e + 3] = v[3];
    }
    __syncthreads();

    float ak[4] = {0.f, 0.f, 0.f, 0.f};
    float av[4] = {0.f, 0.f, 0.f, 0.f};
    const float* wkr = Wk + (size_t)t * DMODEL;
    const float* wvr = Wv + (size_t)t * DMODEL;
#pragma unroll 4
    for (int in = 0; in < DMODEL; in += 4) {
        f32x4_t ku = *(const f32x4_t*)(wkr + in);
        f32x4_t vu = *(const f32x4_t*)(wvr + in);
#pragma unroll
        for (int jj = 0; jj < 4; jj++) {
            ak[jj] = fmaf(fl[jj][in + 0], ku[0], ak[jj]);
            ak[jj] = fmaf(fl[jj][in + 1], ku[1], ak[jj]);
            ak[jj] = fmaf(fl[jj][in + 2], ku[2], ak[jj]);
            ak[jj] = fmaf(fl[jj][in + 3], ku[3], ak[jj]);
            av[jj] = fmaf(fl[jj][in + 0], vu[0], av[jj]);
            av[jj] = fmaf(fl[jj][in + 1], vu[1], av[jj]);
            av[jj] = fmaf(fl[jj][in + 2], vu[2], av[jj]);
            av[jj] = fmaf(fl[jj][in + 3], vu[3], av[jj]);
        }
    }
    float bkv = bk[t];
    float bvv = bv[t];
#pragma unroll
    for (int jj = 0; jj < 4; jj++) {
        k_s[(unsigned)(j0 + jj) * DMODEL + t] = (unsigned short)f2bs((ak[jj] + bkv) * 0.0625f);
        vT[(unsigned)t * MSAMP + (j0 + jj)]   = (unsigned short)f2bs(av[jj] + bvv);
    }
}

// ---------------------------------------------------------------------------
// Fused q -> w -> res -> concat. 128-row tile, 4 waves (2 row x 2 col), MFMA
// 16x16x32 bf16, double-buffered wlds (R14, marginally best).
// ---------------------------------------------------------------------------
#define QS  264
#define WSR 136
#define RS  258
#define WBUF (128 * WSR)                       // u16 elems per wlds buffer
#define MAIN_LDS (128 * QS * 2 + 2 * WBUF * 2) // 137216 B

__global__ __launch_bounds__(256, 1) void main_kernel(
    const float* __restrict__ feat,
    const float* __restrict__ Wq, const float* __restrict__ bq,
    const unsigned short* __restrict__ k_s,
    const unsigned short* __restrict__ vT,
    float* __restrict__ out)
{
    extern __shared__ char smem[];
    unsigned short* qlds = (unsigned short*)smem;
    unsigned short* wlds = (unsigned short*)(smem + 128 * QS * 2);

    const int tid  = threadIdx.x;
    const int ln   = tid & 63;
    const int wid  = tid >> 6;
    const int wr   = wid & 1;
    const int wc   = wid >> 1;
    const int r0   = blockIdx.x * 128;
    const int lrow = ln & 15;
    const int lk   = (ln >> 4) * 8;
    const int crow = (ln >> 4) * 4;

    const f32x4_t fzero = {0.f, 0.f, 0.f, 0.f};

    // ---- phase 1: q = feat @ Wq^T + bq -> bf16 in qlds ----
    f32x4_t qa[4][8];
#pragma unroll
    for (int m = 0; m < 4; m++)
#pragma unroll
        for (int n = 0; n < 8; n++) qa[m][n] = fzero;

#pragma unroll
    for (int kb = 0; kb < DMODEL; kb += 32) {
        bf16x8_t A[4], B[8];
#pragma unroll
        for (int m = 0; m < 4; m++)
            A[m] = cvt8(feat + (size_t)(r0 + wr * 64 + m * 16 + lrow) * DMODEL + kb + lk);
#pragma unroll
        for (int n = 0; n < 8; n++)
            B[n] = cvt8(Wq + (size_t)(wc * 128 + n * 16 + lrow) * DMODEL + kb + lk);
#pragma unroll
        for (int m = 0; m < 4; m++)
#pragma unroll
            for (int n = 0; n < 8; n++)
                qa[m][n] = __builtin_amdgcn_mfma_f32_16x16x32_bf16(
                    A[m], B[n], qa[m][n], 0, 0, 0);
    }
#pragma unroll
    for (int n = 0; n < 8; n++) {
        float bqv = bq[wc * 128 + n * 16 + lrow];
#pragma unroll
        for (int m = 0; m < 4; m++)
#pragma unroll
            for (int r = 0; r < 4; r++)
                qlds[(wr * 64 + m * 16 + crow + r) * QS + wc * 128 + n * 16 + lrow] =
                    (unsigned short)f2bs(qa[m][n][r] + bqv);
    }
    __syncthreads();

    // ---- phase 2: dbuf flash loop ----
    f32x4_t racc[4][8];
#pragma unroll
    for (int m = 0; m < 4; m++)
#pragma unroll
        for (int n = 0; n < 8; n++) racc[m][n] = fzero;

    // prologue: w(0) -> wlds buf 0
    {
        f32x4_t wa[4][4];
#pragma unroll
        for (int m = 0; m < 4; m++)
#pragma unroll
            for (int n = 0; n < 4; n++) wa[m][n] = fzero;
#pragma unroll
        for (int kb = 0; kb < DMODEL; kb += 32) {
            bf16x8_t A[4], B[4];
#pragma unroll
            for (int m = 0; m < 4; m++)
                A[m] = *(const bf16x8_t*)(qlds + (wr * 64 + m * 16 + lrow) * QS + kb + lk);
#pragma unroll
            for (int n = 0; n < 4; n++)
                B[n] = *(const bf16x8_t*)(k_s +
                    (size_t)(wc * 64 + n * 16 + lrow) * DMODEL + kb + lk);
#pragma unroll
            for (int m = 0; m < 4; m++)
#pragma unroll
                for (int n = 0; n < 4; n++)
                    wa[m][n] = __builtin_amdgcn_mfma_f32_16x16x32_bf16(
                        A[m], B[n], wa[m][n], 0, 0, 0);
        }
#pragma unroll
        for (int m = 0; m < 4; m++)
#pragma unroll
            for (int n = 0; n < 4; n++)
#pragma unroll
                for (int r = 0; r < 4; r++)
                    wlds[(wr * 64 + m * 16 + crow + r) * WSR + wc * 64 + n * 16 + lrow] =
                        (unsigned short)f2bs(wa[m][n][r]);
    }
    __syncthreads();

    for (int jb = 0; jb < 8; jb++) {
        const int cur = jb & 1;
        unsigned short* wcur = wlds + cur * WBUF;
        unsigned short* wnxt = wlds + (cur ^ 1) * WBUF;

        // produce w(jb+1) -> wnxt (independent of res(jb); co-scheduled)
        if (jb < 7) {
            f32x4_t wa[4][4];
#pragma unroll
            for (int m = 0; m < 4; m++)
#pragma unroll
                for (int n = 0; n < 4; n++) wa[m][n] = fzero;
#pragma unroll
            for (int kb = 0; kb < DMODEL; kb += 32) {
                bf16x8_t A[4], B[4];
#pragma unroll
                for (int m = 0; m < 4; m++)
                    A[m] = *(const bf16x8_t*)(qlds + (wr * 64 + m * 16 + lrow) * QS + kb + lk);
#pragma unroll
                for (int n = 0; n < 4; n++)
                    B[n] = *(const bf16x8_t*)(k_s +
                        (size_t)((jb + 1) * 128 + wc * 64 + n * 16 + lrow) * DMODEL + kb + lk);
#pragma unroll
                for (int m = 0; m < 4; m++)
#pragma unroll
                    for (int n = 0; n < 4; n++)
                        wa[m][n] = __builtin_amdgcn_mfma_f32_16x16x32_bf16(
                            A[m], B[n], wa[m][n], 0, 0, 0);
            }
#pragma unroll
            for (int m = 0; m < 4; m++)
#pragma unroll
                for (int n = 0; n < 4; n++)
#pragma unroll
                    for (int r = 0; r < 4; r++)
                        wnxt[(wr * 64 + m * 16 + crow + r) * WSR + wc * 64 + n * 16 + lrow] =
                            (unsigned short)f2bs(wa[m][n][r]);
        }

        // consume wcur for res(jb)
#pragma unroll
        for (int kb2 = 0; kb2 < 128; kb2 += 32) {
            bf16x8_t A[4], B[8];
#pragma unroll
            for (int m = 0; m < 4; m++)
                A[m] = *(const bf16x8_t*)(wcur + (wr * 64 + m * 16 + lrow) * WSR + kb2 + lk);
#pragma unroll
            for (int n = 0; n < 8; n++)
                B[n] = *(const bf16x8_t*)(vT +
                    (size_t)(wc * 128 + n * 16 + lrow) * MSAMP + jb * 128 + kb2 + lk);
#pragma unroll
            for (int m = 0; m < 4; m++)
#pragma unroll
                for (int n = 0; n < 8; n++)
                    racc[m][n] = __builtin_amdgcn_mfma_f32_16x16x32_bf16(
                        A[m], B[n], racc[m][n], 0, 0, 0);
        }
        __syncthreads();
    }

    // ---- phase 3: epilogue, f32 res -> LDS, coalesced f32 [res|feat] store ----
    float* rlds = (float*)smem;   // qlds/wlds dead now (final barrier above)
#pragma unroll
    for (int m = 0; m < 4; m++)
#pragma unroll
        for (int n = 0; n < 8; n++)
#pragma unroll
            for (int r = 0; r < 4; r++)
                rlds[(wr * 64 + m * 16 + crow + r) * RS + wc * 128 + n * 16 + lrow] =
                    racc[m][n][r];
    __syncthreads();

#pragma unroll
    for (int base = 0; base < 128; base += 4) {
        int row = base + wid;
        f32x4_t a = *(const f32x4_t*)(rlds + row * RS + ln * 4);
        f32x4_t b = *(const f32x4_t*)(feat + (size_t)(r0 + row) * DMODEL + ln * 4);
        *(f32x4_t*)(out + (size_t)(r0 + row) * 512 + ln * 4)       = a;
        *(f32x4_t*)(out + (size_t)(r0 + row) * 512 + 256 + ln * 4) = b;
    }
}

// ---------------------------------------------------------------------------
extern "C" void kernel_launch(void* const* d_in, const int* in_sizes, int n_in,
                              void* d_out, int out_size, void* d_ws, size_t ws_size,
                              hipStream_t stream) {
    const float* p_xyz = (const float*)d_in[0];
    const float* feat  = (const float*)d_in[1];
    const float* Wq    = (const float*)d_in[2];
    const float* bq    = (const float*)d_in[3];
    const float* Wk    = (const float*)d_in[4];
    const float* bk    = (const float*)d_in[5];
    const float* Wv    = (const float*)d_in[6];
    const float* bv    = (const float*)d_in[7];
    float* out = (float*)d_out;

    char* ws = (char*)d_ws;
    unsigned long long* slots = (unsigned long long*)ws;                //  16 KB [2][NW][SLW]
    int*                idx   = (int*)(ws + 16384);                     //   4 KB
    unsigned short*     k_s   = (unsigned short*)(ws + 32768);          // 512 KB
    unsigned short*     vT    = (unsigned short*)(ws + 32768 + 524288); // 512 KB

    hipMemsetAsync(d_ws, 0, 16384, stream);   // invalidate slots every call

    hipLaunchKernelGGL(fps_kernel, dim3(NW), dim3(64), 0, stream,
                       p_xyz, slots, idx);
    hipLaunchKernelGGL(kv_kernel, dim3(MSAMP / 4), dim3(256), 0, stream,
                       feat, Wk, bk, Wv, bv, idx, k_s, vT);
    hipFuncSetAttribute((const void*)main_kernel,
                        hipFuncAttributeMaxDynamicSharedMemorySize, MAIN_LDS);
    hipLaunchKernelGGL(main_kernel, dim3(N_PTS / 128), dim3(256), MAIN_LDS, stream,
                       feat, Wq, bq, k_s, vT, out);
}

// Round 16
// 933.628 us; speedup vs baseline: 1.5766x; 1.5766x over previous
//
#include <hip/hip_runtime.h>
#include <hip/hip_bf16.h>

#define N_PTS  65536
#define DMODEL 256
#define MSAMP  1024

#define NW    64   // FPS waves = single-wave workgroups (all co-resident)
#define FPT   16   // points per lane: 65536 / (64 * 64)
#define SLW   16   // u64s per slot line: 128B stride, one wave per line
#define NCAND 8    // candidates published per wave (+1 bound slot) — R10 proven

typedef short bf16x8_t __attribute__((ext_vector_type(8)));
typedef float f32x4_t  __attribute__((ext_vector_type(4)));

__device__ __forceinline__ short f2bs(float f) {
    __hip_bfloat16 h = __float2bfloat16(f);   // RNE
    return *reinterpret_cast<short*>(&h);
}

__device__ __forceinline__ bf16x8_t cvt8(const float* p) {
    f32x4_t a = *(const f32x4_t*)(p);
    f32x4_t b = *(const f32x4_t*)(p + 4);
    bf16x8_t r;
#pragma unroll
    for (int i = 0; i < 4; i++) { r[i] = f2bs(a[i]); r[i + 4] = f2bs(b[i]); }
    return r;
}

// exact numpy distance: per-op RN f32, ((dx^2+dy^2)+dz^2), no FMA
__device__ __forceinline__ float dist2(float ax, float ay, float az,
                                       float bx, float by, float bz) {
    float dx = __fsub_rn(ax, bx), dy = __fsub_rn(ay, by), dz = __fsub_rn(az, bz);
    return __fadd_rn(__fadd_rn(__fmul_rn(dx, dx), __fmul_rn(dy, dy)),
                     __fmul_rn(dz, dz));
}
// u64 max via f64 fmax (packs are positive f64 bit patterns; proven R5-R15)
__device__ __forceinline__ unsigned long long dmax64(unsigned long long a,
                                                     unsigned long long b) {
    double r = fmax(__longlong_as_double((long long)a),
                    __longlong_as_double((long long)b));
    return (unsigned long long)__double_as_longlong(r);
}

// ---- R16: full-wave max via DPP (VALU pipe) instead of ds_bpermute --------
// row_shr:1/2/4/8 (0x111..0x118) + row_bcast:15 (0x142) + row_bcast:31
// (0x143); old=0 & bound_ctrl=false -> invalid-source lanes contribute 0,
// a valid identity (all reduced quantities are non-negative). Lane 63 holds
// the wave max; readlane broadcasts it. u32 max == f32 max for non-negative
// floats (IEEE bit-pattern monotone), so one helper serves both.
__device__ __forceinline__ unsigned wave_umax_dpp(unsigned v) {
    unsigned t;
    t = __builtin_amdgcn_update_dpp(0, (int)v, 0x111, 0xF, 0xF, false); v = v > (unsigned)t ? v : (unsigned)t;
    t = __builtin_amdgcn_update_dpp(0, (int)v, 0x112, 0xF, 0xF, false); v = v > (unsigned)t ? v : (unsigned)t;
    t = __builtin_amdgcn_update_dpp(0, (int)v, 0x114, 0xF, 0xF, false); v = v > (unsigned)t ? v : (unsigned)t;
    t = __builtin_amdgcn_update_dpp(0, (int)v, 0x118, 0xF, 0xF, false); v = v > (unsigned)t ? v : (unsigned)t;
    t = __builtin_amdgcn_update_dpp(0, (int)v, 0x142, 0xF, 0xF, false); v = v > (unsigned)t ? v : (unsigned)t;
    t = __builtin_amdgcn_update_dpp(0, (int)v, 0x143, 0xF, 0xF, false); v = v > (unsigned)t ? v : (unsigned)t;
    return (unsigned)__builtin_amdgcn_readlane((int)v, 63);
}
// wave-max of pack (value<<32 | inv_idx), both halves non-negative; ties on
// value resolve to max inv_idx (= smallest point index) — bitwise identical
// to the previous u64 lexicographic butterfly.
__device__ __forceinline__ unsigned long long wave_maxpack(unsigned long long p) {
    unsigned hv = (unsigned)(p >> 32);
    unsigned lv = (unsigned)p;
    unsigned gv = wave_umax_dpp(hv);
    unsigned ml = (hv == gv) ? lv : 0u;
    unsigned gl = wave_umax_dpp(ml);
    return (((unsigned long long)gv) << 32) | gl;
}

// ---------------------------------------------------------------------------
// Batched-candidate FPS, NCAND=8 — R10 skeleton (proven 866us), with every
// 64-lane reduction switched from 6-step shfl_xor butterflies (12 serial
// ds_bpermute) to the DPP reduce above. Protocol, exactness argument, and
// liveness class unchanged.
// ---------------------------------------------------------------------------
__global__ __launch_bounds__(64) void fps_kernel(
    const float*        __restrict__ xyz,      // (N,3) f32
    unsigned long long* __restrict__ slots,    // [2][NW][SLW] u64, zeroed per call
    int*                __restrict__ idx)      // (MSAMP) out
{
    const int l = threadIdx.x;       // 0..63
    const int g = blockIdx.x;        // 0..63
    const int base = g * (FPT * 64) + l;

    float px[FPT], py[FPT], pz[FPT], dd[FPT];
    unsigned long long ivi[FPT];
    const float c0x = xyz[0], c0y = xyz[1], c0z = xyz[2];   // winner 0 = point 0
#pragma unroll
    for (int i = 0; i < FPT; i++) {
        int p = base + i * 64;
        px[i] = xyz[3 * p + 0];
        py[i] = xyz[3 * p + 1];
        pz[i] = xyz[3 * p + 2];
        dd[i] = fminf(1e10f, dist2(px[i], py[i], pz[i], c0x, c0y, c0z));
        ivi[i] = (unsigned long long)(0xFFFFu - (unsigned)p);
    }
    if (g == 0 && l == 0) idx[0] = 0;

    int total = 0, r = 0;
    while (total < MSAMP - 1) {
        ++r;
        // ---- 1) extract top-(NCAND+1) packs ------------------------------
        unsigned long long pk[FPT];
#pragma unroll
        for (int i = 0; i < FPT; i++)
            pk[i] = (((unsigned long long)__float_as_uint(dd[i])) << 32) | ivi[i];

        unsigned long long top[NCAND + 1];
        unsigned long long prev = ~0ull;            // matches no pack
#pragma unroll
        for (int t = 0; t < NCAND + 1; t++) {
            unsigned long long lm = 0;
#pragma unroll
            for (int i = 0; i < FPT; i++) {
                pk[i] = (pk[i] == prev) ? 0ull : pk[i];
                lm = dmax64(lm, pk[i]);
            }
            unsigned long long gt = wave_maxpack(lm);
            top[t] = gt;
            prev = gt;
        }

        // ---- 2) publish (lanes 0..NCAND) + poll --------------------------
        const int ph = r & 1;
        const unsigned rt = (unsigned)(r & 0xFFFF);
        unsigned long long sv = top[0];
#pragma unroll
        for (int t = 1; t <= NCAND; t++) sv = (l == t) ? top[t] : sv;
        sv |= ((unsigned long long)rt) << 16;       // bits 16-31 free in packs
        if (l <= NCAND)
            __hip_atomic_store(slots + ((size_t)(ph * NW + g) * SLW + l), sv,
                               __ATOMIC_RELAXED, __HIP_MEMORY_SCOPE_AGENT);

        const unsigned long long* Q = slots + (size_t)ph * NW * SLW + (size_t)l * SLW;
        unsigned long long u[NCAND + 1];
        for (;;) {
            bool ok = true;
#pragma unroll
            for (int t = 0; t <= NCAND; t++) {
                u[t] = __hip_atomic_load(Q + t, __ATOMIC_RELAXED,
                                         __HIP_MEMORY_SCOPE_AGENT);
                ok &= (((unsigned)(u[t] >> 16) & 0xFFFFu) == rt);
            }
            if (__all(ok)) break;
            __builtin_amdgcn_s_sleep(2);
        }

        // ---- parse: lane l holds wave l's 8 candidates + bound -----------
        float cv[NCAND], cxc[NCAND], cyc[NCAND], czc[NCAND];
        unsigned ici[NCAND];
#pragma unroll
        for (int c = 0; c < NCAND; c++) {
            cv[c]  = __uint_as_float((unsigned)(u[c] >> 32));
            ici[c] = (unsigned)(u[c] & 0xFFFFu);
            int pi = 0xFFFF - (int)ici[c];
            cxc[c] = xyz[3 * pi + 0];
            cyc[c] = xyz[3 * pi + 1];
            czc[c] = xyz[3 * pi + 2];
        }
        float mB = __uint_as_float(
            wave_umax_dpp(__float_as_uint(
                __uint_as_float((unsigned)(u[NCAND] >> 32)))));

        // ---- 3) emission loop (identical on every wave) ------------------
        int kk = 0;
        while (total < MSAMP - 1) {
            unsigned long long lb = 0;
#pragma unroll
            for (int c = 0; c < NCAND; c++)
                lb = dmax64(lb, (((unsigned long long)__float_as_uint(cv[c])) << 32) | ici[c]);
            unsigned long long gb = wave_maxpack(lb);
            float gv = __uint_as_float((unsigned)(gb >> 32));
            if (kk > 0 && !(gv > mB)) break;     // strict >: exact vs unpublished

            int widx = 0xFFFF - (int)(gb & 0xFFFFu);
            if (g == 0 && l == 0) idx[total + 1] = widx;

            // winner coords from the owning lane (packs globally unique)
            float sx = cxc[0], sy = cyc[0], sz = czc[0];
#pragma unroll
            for (int c = 1; c < NCAND; c++) {
                bool h = ((((unsigned long long)__float_as_uint(cv[c])) << 32) | ici[c]) == gb;
                sx = h ? cxc[c] : sx;
                sy = h ? cyc[c] : sy;
                sz = h ? czc[c] : sz;
            }
            unsigned long long mo = __ballot(lb == gb);
            int ol = __ffsll((unsigned long long)mo) - 1;
            float wx = __shfl(sx, ol, 64);
            float wy = __shfl(sy, ol, 64);
            float wz = __shfl(sz, ol, 64);

            // exact min-sequence updates: candidates AND local points
#pragma unroll
            for (int c = 0; c < NCAND; c++)
                cv[c] = fminf(cv[c], dist2(cxc[c], cyc[c], czc[c], wx, wy, wz));
#pragma unroll
            for (int i = 0; i < FPT; i++)
                dd[i] = fminf(dd[i], dist2(px[i], py[i], pz[i], wx, wy, wz));

            total++; kk++;
        }
    }
}

// ---------------------------------------------------------------------------
// Gather + K/V projection in f32; outputs bf16. k pre-scaled by 1/16 (exact),
// row-major (j,k); v stored transposed (d,j).   [R10 verbatim, proven]
// ---------------------------------------------------------------------------
__global__ __launch_bounds__(256) void kv_kernel(
    const float* __restrict__ feat,
    const float* __restrict__ Wk, const float* __restrict__ bk,
    const float* __restrict__ Wv, const float* __restrict__ bv,
    const int* __restrict__ idx,
    unsigned short* __restrict__ k_s,   // (MSAMP, DMODEL) bf16, * 1/16
    unsigned short* __restrict__ vT)    // (DMODEL, MSAMP) bf16
{
    __shared__ float fl[4][DMODEL];
    const int t  = threadIdx.x;
    const int j0 = blockIdx.x * 4;
    {
        int jj = t >> 6;
        int e  = (t & 63) * 4;
        int src = idx[j0 + jj];
        f32x4_t v = *(const f32x4_t*)(feat + (size_t)src * DMODEL + e);
        fl[jj][e + 0] = v[0];
        fl[jj][e + 1] = v[1];
        fl[jj][e + 2] = v[2];
        fl[jj][e + 3] = v[3];
    }
    __syncthreads();

    float ak[4] = {0.f, 0.f, 0.f, 0.f};
    float av[4] = {0.f, 0.f, 0.f, 0.f};
    const float* wkr = Wk + (size_t)t * DMODEL;
    const float* wvr = Wv + (size_t)t * DMODEL;
#pragma unroll 4
    for (int in = 0; in < DMODEL; in += 4) {
        f32x4_t ku = *(const f32x4_t*)(wkr + in);
        f32x4_t vu = *(const f32x4_t*)(wvr + in);
#pragma unroll
        for (int jj = 0; jj < 4; jj++) {
            ak[jj] = fmaf(fl[jj][in + 0], ku[0], ak[jj]);
            ak[jj] = fmaf(fl[jj][in + 1], ku[1], ak[jj]);
            ak[jj] = fmaf(fl[jj][in + 2], ku[2], ak[jj]);
            ak[jj] = fmaf(fl[jj][in + 3], ku[3], ak[jj]);
            av[jj] = fmaf(fl[jj][in + 0], vu[0], av[jj]);
            av[jj] = fmaf(fl[jj][in + 1], vu[1], av[jj]);
            av[jj] = fmaf(fl[jj][in + 2], vu[2], av[jj]);
            av[jj] = fmaf(fl[jj][in + 3], vu[3], av[jj]);
        }
    }
    float bkv = bk[t];
    float bvv = bv[t];
#pragma unroll
    for (int jj = 0; jj < 4; jj++) {
        k_s[(unsigned)(j0 + jj) * DMODEL + t] = (unsigned short)f2bs((ak[jj] + bkv) * 0.0625f);
        vT[(unsigned)t * MSAMP + (j0 + jj)]   = (unsigned short)f2bs(av[jj] + bvv);
    }
}

// ---------------------------------------------------------------------------
// Fused q -> w -> res -> concat. 128-row tile, 4 waves (2 row x 2 col), MFMA
// 16x16x32 bf16, double-buffered wlds.   [R14 verbatim, proven best tail]
// ---------------------------------------------------------------------------
#define QS  264
#define WSR 136
#define RS  258
#define WBUF (128 * WSR)                       // u16 elems per wlds buffer
#define MAIN_LDS (128 * QS * 2 + 2 * WBUF * 2) // 137216 B

__global__ __launch_bounds__(256, 1) void main_kernel(
    const float* __restrict__ feat,
    const float* __restrict__ Wq, const float* __restrict__ bq,
    const unsigned short* __restrict__ k_s,
    const unsigned short* __restrict__ vT,
    float* __restrict__ out)
{
    extern __shared__ char smem[];
    unsigned short* qlds = (unsigned short*)smem;
    unsigned short* wlds = (unsigned short*)(smem + 128 * QS * 2);

    const int tid  = threadIdx.x;
    const int ln   = tid & 63;
    const int wid  = tid >> 6;
    const int wr   = wid & 1;
    const int wc   = wid >> 1;
    const int r0   = blockIdx.x * 128;
    const int lrow = ln & 15;
    const int lk   = (ln >> 4) * 8;
    const int crow = (ln >> 4) * 4;

    const f32x4_t fzero = {0.f, 0.f, 0.f, 0.f};

    // ---- phase 1: q = feat @ Wq^T + bq -> bf16 in qlds ----
    f32x4_t qa[4][8];
#pragma unroll
    for (int m = 0; m < 4; m++)
#pragma unroll
        for (int n = 0; n < 8; n++) qa[m][n] = fzero;

#pragma unroll
    for (int kb = 0; kb < DMODEL; kb += 32) {
        bf16x8_t A[4], B[8];
#pragma unroll
        for (int m = 0; m < 4; m++)
            A[m] = cvt8(feat + (size_t)(r0 + wr * 64 + m * 16 + lrow) * DMODEL + kb + lk);
#pragma unroll
        for (int n = 0; n < 8; n++)
            B[n] = cvt8(Wq + (size_t)(wc * 128 + n * 16 + lrow) * DMODEL + kb + lk);
#pragma unroll
        for (int m = 0; m < 4; m++)
#pragma unroll
            for (int n = 0; n < 8; n++)
                qa[m][n] = __builtin_amdgcn_mfma_f32_16x16x32_bf16(
                    A[m], B[n], qa[m][n], 0, 0, 0);
    }
#pragma unroll
    for (int n = 0; n < 8; n++) {
        float bqv = bq[wc * 128 + n * 16 + lrow];
#pragma unroll
        for (int m = 0; m < 4; m++)
#pragma unroll
            for (int r = 0; r < 4; r++)
                qlds[(wr * 64 + m * 16 + crow + r) * QS + wc * 128 + n * 16 + lrow] =
                    (unsigned short)f2bs(qa[m][n][r] + bqv);
    }
    __syncthreads();

    // ---- phase 2: dbuf flash loop ----
    f32x4_t racc[4][8];
#pragma unroll
    for (int m = 0; m < 4; m++)
#pragma unroll
        for (int n = 0; n < 8; n++) racc[m][n] = fzero;

    // prologue: w(0) -> wlds buf 0
    {
        f32x4_t wa[4][4];
#pragma unroll
        for (int m = 0; m < 4; m++)
#pragma unroll
            for (int n = 0; n < 4; n++) wa[m][n] = fzero;
#pragma unroll
        for (int kb = 0; kb < DMODEL; kb += 32) {
            bf16x8_t A[4], B[4];
#pragma unroll
            for (int m = 0; m < 4; m++)
                A[m] = *(const bf16x8_t*)(qlds + (wr * 64 + m * 16 + lrow) * QS + kb + lk);
#pragma unroll
            for (int n = 0; n < 4; n++)
                B[n] = *(const bf16x8_t*)(k_s +
                    (size_t)(wc * 64 + n * 16 + lrow) * DMODEL + kb + lk);
#pragma unroll
            for (int m = 0; m < 4; m++)
#pragma unroll
                for (int n = 0; n < 4; n++)
                    wa[m][n] = __builtin_amdgcn_mfma_f32_16x16x32_bf16(
                        A[m], B[n], wa[m][n], 0, 0, 0);
        }
#pragma unroll
        for (int m = 0; m < 4; m++)
#pragma unroll
            for (int n = 0; n < 4; n++)
#pragma unroll
                for (int r = 0; r < 4; r++)
                    wlds[(wr * 64 + m * 16 + crow + r) * WSR + wc * 64 + n * 16 + lrow] =
                        (unsigned short)f2bs(wa[m][n][r]);
    }
    __syncthreads();

    for (int jb = 0; jb < 8; jb++) {
        const int cur = jb & 1;
        unsigned short* wcur = wlds + cur * WBUF;
        unsigned short* wnxt = wlds + (cur ^ 1) * WBUF;

        // produce w(jb+1) -> wnxt (independent of res(jb); co-scheduled)
        if (jb < 7) {
            f32x4_t wa[4][4];
#pragma unroll
            for (int m = 0; m < 4; m++)
#pragma unroll
                for (int n = 0; n < 4; n++) wa[m][n] = fzero;
#pragma unroll
            for (int kb = 0; kb < DMODEL; kb += 32) {
                bf16x8_t A[4], B[4];
#pragma unroll
                for (int m = 0; m < 4; m++)
                    A[m] = *(const bf16x8_t*)(qlds + (wr * 64 + m * 16 + lrow) * QS + kb + lk);
#pragma unroll
                for (int n = 0; n < 4; n++)
                    B[n] = *(const bf16x8_t*)(k_s +
                        (size_t)((jb + 1) * 128 + wc * 64 + n * 16 + lrow) * DMODEL + kb + lk);
#pragma unroll
                for (int m = 0; m < 4; m++)
#pragma unroll
                    for (int n = 0; n < 4; n++)
                        wa[m][n] = __builtin_amdgcn_mfma_f32_16x16x32_bf16(
                            A[m], B[n], wa[m][n], 0, 0, 0);
            }
#pragma unroll
            for (int m = 0; m < 4; m++)
#pragma unroll
                for (int n = 0; n < 4; n++)
#pragma unroll
                    for (int r = 0; r < 4; r++)
                        wnxt[(wr * 64 + m * 16 + crow + r) * WSR + wc * 64 + n * 16 + lrow] =
                            (unsigned short)f2bs(wa[m][n][r]);
        }

        // consume wcur for res(jb)
#pragma unroll
        for (int kb2 = 0; kb2 < 128; kb2 += 32) {
            bf16x8_t A[4], B[8];
#pragma unroll
            for (int m = 0; m < 4; m++)
                A[m] = *(const bf16x8_t*)(wcur + (wr * 64 + m * 16 + lrow) * WSR + kb2 + lk);
#pragma unroll
            for (int n = 0; n < 8; n++)
                B[n] = *(const bf16x8_t*)(vT +
                    (size_t)(wc * 128 + n * 16 + lrow) * MSAMP + jb * 128 + kb2 + lk);
#pragma unroll
            for (int m = 0; m < 4; m++)
#pragma unroll
                for (int n = 0; n < 8; n++)
                    racc[m][n] = __builtin_amdgcn_mfma_f32_16x16x32_bf16(
                        A[m], B[n], racc[m][n], 0, 0, 0);
        }
        __syncthreads();
    }

    // ---- phase 3: epilogue, f32 res -> LDS, coalesced f32 [res|feat] store ----
    float* rlds = (float*)smem;   // qlds/wlds dead now (final barrier above)
#pragma unroll
    for (int m = 0; m < 4; m++)
#pragma unroll
        for (int n = 0; n < 8; n++)
#pragma unroll
            for (int r = 0; r < 4; r++)
                rlds[(wr * 64 + m * 16 + crow + r) * RS + wc * 128 + n * 16 + lrow] =
                    racc[m][n][r];
    __syncthreads();

#pragma unroll
    for (int base = 0; base < 128; base += 4) {
        int row = base + wid;
        f32x4_t a = *(const f32x4_t*)(rlds + row * RS + ln * 4);
        f32x4_t b = *(const f32x4_t*)(feat + (size_t)(r0 + row) * DMODEL + ln * 4);
        *(f32x4_t*)(out + (size_t)(r0 + row) * 512 + ln * 4)       = a;
        *(f32x4_t*)(out + (size_t)(r0 + row) * 512 + 256 + ln * 4) = b;
    }
}

// ---------------------------------------------------------------------------
extern "C" void kernel_launch(void* const* d_in, const int* in_sizes, int n_in,
                              void* d_out, int out_size, void* d_ws, size_t ws_size,
                              hipStream_t stream) {
    const float* p_xyz = (const float*)d_in[0];
    const float* feat  = (const float*)d_in[1];
    const float* Wq    = (const float*)d_in[2];
    const float* bq    = (const float*)d_in[3];
    const float* Wk    = (const float*)d_in[4];
    const float* bk    = (const float*)d_in[5];
    const float* Wv    = (const float*)d_in[6];
    const float* bv    = (const float*)d_in[7];
    float* out = (float*)d_out;

    char* ws = (char*)d_ws;
    unsigned long long* slots = (unsigned long long*)ws;                //  16 KB [2][NW][SLW]
    int*                idx   = (int*)(ws + 16384);                     //   4 KB
    unsigned short*     k_s   = (unsigned short*)(ws + 32768);          // 512 KB
    unsigned short*     vT    = (unsigned short*)(ws + 32768 + 524288); // 512 KB

    hipMemsetAsync(d_ws, 0, 16384, stream);   // invalidate slots every call

    hipLaunchKernelGGL(fps_kernel, dim3(NW), dim3(64), 0, stream,
                       p_xyz, slots, idx);
    hipLaunchKernelGGL(kv_kernel, dim3(MSAMP / 4), dim3(256), 0, stream,
                       feat, Wk, bk, Wv, bv, idx, k_s, vT);
    hipFuncSetAttribute((const void*)main_kernel,
                        hipFuncAttributeMaxDynamicSharedMemorySize, MAIN_LDS);
    hipLaunchKernelGGL(main_kernel, dim3(N_PTS / 128), dim3(256), MAIN_LDS, stream,
                       feat, Wq, bq, k_s, vT, out);
}

// Round 17
// 870.953 us; speedup vs baseline: 1.6901x; 1.0720x over previous
//
#include <hip/hip_runtime.h>
#include <hip/hip_bf16.h>

#define N_PTS  65536
#define DMODEL 256
#define MSAMP  1024

#define NW    64   // FPS waves = single-wave workgroups (all co-resident)
#define FPT   16   // points per lane: 65536 / (64 * 64)
#define FPP   8    // point PAIRS per lane (f32x2 packed math)
#define SLW   16   // u64s per slot line: 128B stride, one wave per line
#define NCAND 8    // candidates published per wave (+1 bound slot) — R10 proven

typedef short bf16x8_t __attribute__((ext_vector_type(8)));
typedef float f32x4_t  __attribute__((ext_vector_type(4)));
typedef float f32x2_t  __attribute__((ext_vector_type(2)));

__device__ __forceinline__ short f2bs(float f) {
    __hip_bfloat16 h = __float2bfloat16(f);   // RNE
    return *reinterpret_cast<short*>(&h);
}

__device__ __forceinline__ bf16x8_t cvt8(const float* p) {
    f32x4_t a = *(const f32x4_t*)(p);
    f32x4_t b = *(const f32x4_t*)(p + 4);
    bf16x8_t r;
#pragma unroll
    for (int i = 0; i < 4; i++) { r[i] = f2bs(a[i]); r[i + 4] = f2bs(b[i]); }
    return r;
}

// exact numpy distance: per-op RN f32, ((dx^2+dy^2)+dz^2), no FMA
__device__ __forceinline__ float dist2(float ax, float ay, float az,
                                       float bx, float by, float bz) {
    float dx = __fsub_rn(ax, bx), dy = __fsub_rn(ay, by), dz = __fsub_rn(az, bz);
    return __fadd_rn(__fadd_rn(__fmul_rn(dx, dx), __fmul_rn(dy, dy)),
                     __fmul_rn(dz, dz));
}
// u64 max via f64 fmax (packs are positive f64 bit patterns; proven R5-R16)
__device__ __forceinline__ unsigned long long dmax64(unsigned long long a,
                                                     unsigned long long b) {
    double r = fmax(__longlong_as_double((long long)a),
                    __longlong_as_double((long long)b));
    return (unsigned long long)__double_as_longlong(r);
}

// ---- full-wave max via DPP (VALU pipe) — R16 proven ----------------------
__device__ __forceinline__ unsigned wave_umax_dpp(unsigned v) {
    unsigned t;
    t = __builtin_amdgcn_update_dpp(0, (int)v, 0x111, 0xF, 0xF, false); v = v > (unsigned)t ? v : (unsigned)t;
    t = __builtin_amdgcn_update_dpp(0, (int)v, 0x112, 0xF, 0xF, false); v = v > (unsigned)t ? v : (unsigned)t;
    t = __builtin_amdgcn_update_dpp(0, (int)v, 0x114, 0xF, 0xF, false); v = v > (unsigned)t ? v : (unsigned)t;
    t = __builtin_amdgcn_update_dpp(0, (int)v, 0x118, 0xF, 0xF, false); v = v > (unsigned)t ? v : (unsigned)t;
    t = __builtin_amdgcn_update_dpp(0, (int)v, 0x142, 0xF, 0xF, false); v = v > (unsigned)t ? v : (unsigned)t;
    t = __builtin_amdgcn_update_dpp(0, (int)v, 0x143, 0xF, 0xF, false); v = v > (unsigned)t ? v : (unsigned)t;
    return (unsigned)__builtin_amdgcn_readlane((int)v, 63);
}
__device__ __forceinline__ unsigned long long wave_maxpack(unsigned long long p) {
    unsigned hv = (unsigned)(p >> 32);
    unsigned lv = (unsigned)p;
    unsigned gv = wave_umax_dpp(hv);
    unsigned ml = (hv == gv) ? lv : 0u;
    unsigned gl = wave_umax_dpp(ml);
    return (((unsigned long long)gv) << 32) | gl;
}

// ---------------------------------------------------------------------------
// Batched-candidate FPS, NCAND=8, DPP reduces (R16, 702us). R17 change:
// points and candidates held as f32x2 PAIRS so the distance-update chains
// (dx=a-b; d=((dx*dx+dy*dy)+dz*dz)) compile to packed v_pk_add/mul_f32
// (gfx950 full-rate packed fp32) — 10 issue slots per 2 points vs 18.
// `#pragma clang fp contract(off)` keeps mul-then-add per-op RN (numpy
// semantics; no FMA contraction). Per-component arithmetic is bitwise
// identical to the scalar version; selection and protocol unchanged.
// ---------------------------------------------------------------------------
#pragma clang fp contract(off)
__global__ __launch_bounds__(64) void fps_kernel(
    const float*        __restrict__ xyz,      // (N,3) f32
    unsigned long long* __restrict__ slots,    // [2][NW][SLW] u64, zeroed per call
    int*                __restrict__ idx)      // (MSAMP) out
{
    const int l = threadIdx.x;       // 0..63
    const int g = blockIdx.x;        // 0..63
    const int base = g * (FPT * 64) + l;

    f32x2_t px2[FPP], py2[FPP], pz2[FPP], dd2[FPP];
    unsigned long long ivi[FPT];
    const float c0x = xyz[0], c0y = xyz[1], c0z = xyz[2];   // winner 0 = point 0
    {
        f32x2_t w0x = {c0x, c0x}, w0y = {c0y, c0y}, w0z = {c0z, c0z};
#pragma unroll
        for (int i = 0; i < FPP; i++) {
            int p0 = base + (2 * i) * 64;
            int p1 = base + (2 * i + 1) * 64;
            px2[i].x = xyz[3 * p0 + 0]; px2[i].y = xyz[3 * p1 + 0];
            py2[i].x = xyz[3 * p0 + 1]; py2[i].y = xyz[3 * p1 + 1];
            pz2[i].x = xyz[3 * p0 + 2]; pz2[i].y = xyz[3 * p1 + 2];
            ivi[2 * i]     = (unsigned long long)(0xFFFFu - (unsigned)p0);
            ivi[2 * i + 1] = (unsigned long long)(0xFFFFu - (unsigned)p1);
            f32x2_t dx = px2[i] - w0x, dy = py2[i] - w0y, dz = pz2[i] - w0z;
            f32x2_t d  = (dx * dx + dy * dy) + dz * dz;   // contract off: RN each op
            dd2[i].x = fminf(1e10f, d.x);
            dd2[i].y = fminf(1e10f, d.y);
        }
    }
    if (g == 0 && l == 0) idx[0] = 0;

    int total = 0, r = 0;
    while (total < MSAMP - 1) {
        ++r;
        // ---- 1) extract top-(NCAND+1) packs ------------------------------
        unsigned long long pk[FPT];
#pragma unroll
        for (int i = 0; i < FPP; i++) {
            pk[2 * i]     = (((unsigned long long)__float_as_uint(dd2[i].x)) << 32) | ivi[2 * i];
            pk[2 * i + 1] = (((unsigned long long)__float_as_uint(dd2[i].y)) << 32) | ivi[2 * i + 1];
        }

        unsigned long long top[NCAND + 1];
        unsigned long long prev = ~0ull;            // matches no pack
#pragma unroll
        for (int t = 0; t < NCAND + 1; t++) {
            unsigned long long lm = 0;
#pragma unroll
            for (int i = 0; i < FPT; i++) {
                pk[i] = (pk[i] == prev) ? 0ull : pk[i];
                lm = dmax64(lm, pk[i]);
            }
            unsigned long long gt = wave_maxpack(lm);
            top[t] = gt;
            prev = gt;
        }

        // ---- 2) publish (lanes 0..NCAND) + poll --------------------------
        const int ph = r & 1;
        const unsigned rt = (unsigned)(r & 0xFFFF);
        unsigned long long sv = top[0];
#pragma unroll
        for (int t = 1; t <= NCAND; t++) sv = (l == t) ? top[t] : sv;
        sv |= ((unsigned long long)rt) << 16;       // bits 16-31 free in packs
        if (l <= NCAND)
            __hip_atomic_store(slots + ((size_t)(ph * NW + g) * SLW + l), sv,
                               __ATOMIC_RELAXED, __HIP_MEMORY_SCOPE_AGENT);

        const unsigned long long* Q = slots + (size_t)ph * NW * SLW + (size_t)l * SLW;
        unsigned long long u[NCAND + 1];
        for (;;) {
            bool ok = true;
#pragma unroll
            for (int t = 0; t <= NCAND; t++) {
                u[t] = __hip_atomic_load(Q + t, __ATOMIC_RELAXED,
                                         __HIP_MEMORY_SCOPE_AGENT);
                ok &= (((unsigned)(u[t] >> 16) & 0xFFFFu) == rt);
            }
            if (__all(ok)) break;
            __builtin_amdgcn_s_sleep(2);
        }

        // ---- parse: lane l holds wave l's 8 candidates (as 4 pairs) ------
        f32x2_t cv2[NCAND / 2], cx2[NCAND / 2], cy2[NCAND / 2], cz2[NCAND / 2];
        unsigned ici[NCAND];
#pragma unroll
        for (int c = 0; c < NCAND / 2; c++) {
            unsigned long long u0 = u[2 * c], u1 = u[2 * c + 1];
            cv2[c].x = __uint_as_float((unsigned)(u0 >> 32));
            cv2[c].y = __uint_as_float((unsigned)(u1 >> 32));
            ici[2 * c]     = (unsigned)(u0 & 0xFFFFu);
            ici[2 * c + 1] = (unsigned)(u1 & 0xFFFFu);
            int p0 = 0xFFFF - (int)ici[2 * c];
            int p1 = 0xFFFF - (int)ici[2 * c + 1];
            cx2[c].x = xyz[3 * p0 + 0]; cx2[c].y = xyz[3 * p1 + 0];
            cy2[c].x = xyz[3 * p0 + 1]; cy2[c].y = xyz[3 * p1 + 1];
            cz2[c].x = xyz[3 * p0 + 2]; cz2[c].y = xyz[3 * p1 + 2];
        }
        float mB = __uint_as_float(wave_umax_dpp((unsigned)(u[NCAND] >> 32)));

        // ---- 3) emission loop (identical on every wave) ------------------
        int kk = 0;
        while (total < MSAMP - 1) {
            unsigned long long lb = 0;
#pragma unroll
            for (int c = 0; c < NCAND / 2; c++) {
                lb = dmax64(lb, (((unsigned long long)__float_as_uint(cv2[c].x)) << 32) | ici[2 * c]);
                lb = dmax64(lb, (((unsigned long long)__float_as_uint(cv2[c].y)) << 32) | ici[2 * c + 1]);
            }
            unsigned long long gb = wave_maxpack(lb);
            float gv = __uint_as_float((unsigned)(gb >> 32));
            if (kk > 0 && !(gv > mB)) break;     // strict >: exact vs unpublished

            int widx = 0xFFFF - (int)(gb & 0xFFFFu);
            if (g == 0 && l == 0) idx[total + 1] = widx;

            // winner coords from the owning lane (packs globally unique)
            float sx = cx2[0].x, sy = cy2[0].x, sz = cz2[0].x;
#pragma unroll
            for (int c = 0; c < NCAND / 2; c++) {
                bool h0 = ((((unsigned long long)__float_as_uint(cv2[c].x)) << 32) | ici[2 * c]) == gb;
                bool h1 = ((((unsigned long long)__float_as_uint(cv2[c].y)) << 32) | ici[2 * c + 1]) == gb;
                sx = h0 ? cx2[c].x : sx; sx = h1 ? cx2[c].y : sx;
                sy = h0 ? cy2[c].x : sy; sy = h1 ? cy2[c].y : sy;
                sz = h0 ? cz2[c].x : sz; sz = h1 ? cz2[c].y : sz;
            }
            unsigned long long mo = __ballot(lb == gb);
            int ol = __ffsll((unsigned long long)mo) - 1;
            float wx = __shfl(sx, ol, 64);
            float wy = __shfl(sy, ol, 64);
            float wz = __shfl(sz, ol, 64);

            f32x2_t wx2 = {wx, wx}, wy2 = {wy, wy}, wz2 = {wz, wz};
            // exact min-sequence updates: candidates AND local points (packed)
#pragma unroll
            for (int c = 0; c < NCAND / 2; c++) {
                f32x2_t dx = cx2[c] - wx2, dy = cy2[c] - wy2, dz = cz2[c] - wz2;
                f32x2_t d  = (dx * dx + dy * dy) + dz * dz;
                cv2[c].x = fminf(cv2[c].x, d.x);
                cv2[c].y = fminf(cv2[c].y, d.y);
            }
#pragma unroll
            for (int i = 0; i < FPP; i++) {
                f32x2_t dx = px2[i] - wx2, dy = py2[i] - wy2, dz = pz2[i] - wz2;
                f32x2_t d  = (dx * dx + dy * dy) + dz * dz;
                dd2[i].x = fminf(dd2[i].x, d.x);
                dd2[i].y = fminf(dd2[i].y, d.y);
            }

            total++; kk++;
        }
    }
}
#pragma clang fp contract(on)

// ---------------------------------------------------------------------------
// Gather + K/V projection in f32; outputs bf16. k pre-scaled by 1/16 (exact),
// row-major (j,k); v stored transposed (d,j).   [R10 verbatim, proven]
// ---------------------------------------------------------------------------
__global__ __launch_bounds__(256) void kv_kernel(
    const float* __restrict__ feat,
    const float* __restrict__ Wk, const float* __restrict__ bk,
    const float* __restrict__ Wv, const float* __restrict__ bv,
    const int* __restrict__ idx,
    unsigned short* __restrict__ k_s,   // (MSAMP, DMODEL) bf16, * 1/16
    unsigned short* __restrict__ vT)    // (DMODEL, MSAMP) bf16
{
    __shared__ float fl[4][DMODEL];
    const int t  = threadIdx.x;
    const int j0 = blockIdx.x * 4;
    {
        int jj = t >> 6;
        int e  = (t & 63) * 4;
        int src = idx[j0 + jj];
        f32x4_t v = *(const f32x4_t*)(feat + (size_t)src * DMODEL + e);
        fl[jj][e + 0] = v[0];
        fl[jj][e + 1] = v[1];
        fl[jj][e + 2] = v[2];
        fl[jj][e + 3] = v[3];
    }
    __syncthreads();

    float ak[4] = {0.f, 0.f, 0.f, 0.f};
    float av[4] = {0.f, 0.f, 0.f, 0.f};
    const float* wkr = Wk + (size_t)t * DMODEL;
    const float* wvr = Wv + (size_t)t * DMODEL;
#pragma unroll 4
    for (int in = 0; in < DMODEL; in += 4) {
        f32x4_t ku = *(const f32x4_t*)(wkr + in);
        f32x4_t vu = *(const f32x4_t*)(wvr + in);
#pragma unroll
        for (int jj = 0; jj < 4; jj++) {
            ak[jj] = fmaf(fl[jj][in + 0], ku[0], ak[jj]);
            ak[jj] = fmaf(fl[jj][in + 1], ku[1], ak[jj]);
            ak[jj] = fmaf(fl[jj][in + 2], ku[2], ak[jj]);
            ak[jj] = fmaf(fl[jj][in + 3], ku[3], ak[jj]);
            av[jj] = fmaf(fl[jj][in + 0], vu[0], av[jj]);
            av[jj] = fmaf(fl[jj][in + 1], vu[1], av[jj]);
            av[jj] = fmaf(fl[jj][in + 2], vu[2], av[jj]);
            av[jj] = fmaf(fl[jj][in + 3], vu[3], av[jj]);
        }
    }
    float bkv = bk[t];
    float bvv = bv[t];
#pragma unroll
    for (int jj = 0; jj < 4; jj++) {
        k_s[(unsigned)(j0 + jj) * DMODEL + t] = (unsigned short)f2bs((ak[jj] + bkv) * 0.0625f);
        vT[(unsigned)t * MSAMP + (j0 + jj)]   = (unsigned short)f2bs(av[jj] + bvv);
    }
}

// ---------------------------------------------------------------------------
// Fused q -> w -> res -> concat. 128-row tile, 4 waves (2 row x 2 col), MFMA
// 16x16x32 bf16, double-buffered wlds.   [R14 verbatim, proven best tail]
// ---------------------------------------------------------------------------
#define QS  264
#define WSR 136
#define RS  258
#define WBUF (128 * WSR)                       // u16 elems per wlds buffer
#define MAIN_LDS (128 * QS * 2 + 2 * WBUF * 2) // 137216 B

__global__ __launch_bounds__(256, 1) void main_kernel(
    const float* __restrict__ feat,
    const float* __restrict__ Wq, const float* __restrict__ bq,
    const unsigned short* __restrict__ k_s,
    const unsigned short* __restrict__ vT,
    float* __restrict__ out)
{
    extern __shared__ char smem[];
    unsigned short* qlds = (unsigned short*)smem;
    unsigned short* wlds = (unsigned short*)(smem + 128 * QS * 2);

    const int tid  = threadIdx.x;
    const int ln   = tid & 63;
    const int wid  = tid >> 6;
    const int wr   = wid & 1;
    const int wc   = wid >> 1;
    const int r0   = blockIdx.x * 128;
    const int lrow = ln & 15;
    const int lk   = (ln >> 4) * 8;
    const int crow = (ln >> 4) * 4;

    const f32x4_t fzero = {0.f, 0.f, 0.f, 0.f};

    // ---- phase 1: q = feat @ Wq^T + bq -> bf16 in qlds ----
    f32x4_t qa[4][8];
#pragma unroll
    for (int m = 0; m < 4; m++)
#pragma unroll
        for (int n = 0; n < 8; n++) qa[m][n] = fzero;

#pragma unroll
    for (int kb = 0; kb < DMODEL; kb += 32) {
        bf16x8_t A[4], B[8];
#pragma unroll
        for (int m = 0; m < 4; m++)
            A[m] = cvt8(feat + (size_t)(r0 + wr * 64 + m * 16 + lrow) * DMODEL + kb + lk);
#pragma unroll
        for (int n = 0; n < 8; n++)
            B[n] = cvt8(Wq + (size_t)(wc * 128 + n * 16 + lrow) * DMODEL + kb + lk);
#pragma unroll
        for (int m = 0; m < 4; m++)
#pragma unroll
            for (int n = 0; n < 8; n++)
                qa[m][n] = __builtin_amdgcn_mfma_f32_16x16x32_bf16(
                    A[m], B[n], qa[m][n], 0, 0, 0);
    }
#pragma unroll
    for (int n = 0; n < 8; n++) {
        float bqv = bq[wc * 128 + n * 16 + lrow];
#pragma unroll
        for (int m = 0; m < 4; m++)
#pragma unroll
            for (int r = 0; r < 4; r++)
                qlds[(wr * 64 + m * 16 + crow + r) * QS + wc * 128 + n * 16 + lrow] =
                    (unsigned short)f2bs(qa[m][n][r] + bqv);
    }
    __syncthreads();

    // ---- phase 2: dbuf flash loop ----
    f32x4_t racc[4][8];
#pragma unroll
    for (int m = 0; m < 4; m++)
#pragma unroll
        for (int n = 0; n < 8; n++) racc[m][n] = fzero;

    // prologue: w(0) -> wlds buf 0
    {
        f32x4_t wa[4][4];
#pragma unroll
        for (int m = 0; m < 4; m++)
#pragma unroll
            for (int n = 0; n < 4; n++) wa[m][n] = fzero;
#pragma unroll
        for (int kb = 0; kb < DMODEL; kb += 32) {
            bf16x8_t A[4], B[4];
#pragma unroll
            for (int m = 0; m < 4; m++)
                A[m] = *(const bf16x8_t*)(qlds + (wr * 64 + m * 16 + lrow) * QS + kb + lk);
#pragma unroll
            for (int n = 0; n < 4; n++)
                B[n] = *(const bf16x8_t*)(k_s +
                    (size_t)(wc * 64 + n * 16 + lrow) * DMODEL + kb + lk);
#pragma unroll
            for (int m = 0; m < 4; m++)
#pragma unroll
                for (int n = 0; n < 4; n++)
                    wa[m][n] = __builtin_amdgcn_mfma_f32_16x16x32_bf16(
                        A[m], B[n], wa[m][n], 0, 0, 0);
        }
#pragma unroll
        for (int m = 0; m < 4; m++)
#pragma unroll
            for (int n = 0; n < 4; n++)
#pragma unroll
                for (int r = 0; r < 4; r++)
                    wlds[(wr * 64 + m * 16 + crow + r) * WSR + wc * 64 + n * 16 + lrow] =
                        (unsigned short)f2bs(wa[m][n][r]);
    }
    __syncthreads();

    for (int jb = 0; jb < 8; jb++) {
        const int cur = jb & 1;
        unsigned short* wcur = wlds + cur * WBUF;
        unsigned short* wnxt = wlds + (cur ^ 1) * WBUF;

        // produce w(jb+1) -> wnxt (independent of res(jb); co-scheduled)
        if (jb < 7) {
            f32x4_t wa[4][4];
#pragma unroll
            for (int m = 0; m < 4; m++)
#pragma unroll
                for (int n = 0; n < 4; n++) wa[m][n] = fzero;
#pragma unroll
            for (int kb = 0; kb < DMODEL; kb += 32) {
                bf16x8_t A[4], B[4];
#pragma unroll
                for (int m = 0; m < 4; m++)
                    A[m] = *(const bf16x8_t*)(qlds + (wr * 64 + m * 16 + lrow) * QS + kb + lk);
#pragma unroll
                for (int n = 0; n < 4; n++)
                    B[n] = *(const bf16x8_t*)(k_s +
                        (size_t)((jb + 1) * 128 + wc * 64 + n * 16 + lrow) * DMODEL + kb + lk);
#pragma unroll
                for (int m = 0; m < 4; m++)
#pragma unroll
                    for (int n = 0; n < 4; n++)
                        wa[m][n] = __builtin_amdgcn_mfma_f32_16x16x32_bf16(
                            A[m], B[n], wa[m][n], 0, 0, 0);
            }
#pragma unroll
            for (int m = 0; m < 4; m++)
#pragma unroll
                for (int n = 0; n < 4; n++)
#pragma unroll
                    for (int r = 0; r < 4; r++)
                        wnxt[(wr * 64 + m * 16 + crow + r) * WSR + wc * 64 + n * 16 + lrow] =
                            (unsigned short)f2bs(wa[m][n][r]);
        }

        // consume wcur for res(jb)
#pragma unroll
        for (int kb2 = 0; kb2 < 128; kb2 += 32) {
            bf16x8_t A[4], B[8];
#pragma unroll
            for (int m = 0; m < 4; m++)
                A[m] = *(const bf16x8_t*)(wcur + (wr * 64 + m * 16 + lrow) * WSR + kb2 + lk);
#pragma unroll
            for (int n = 0; n < 8; n++)
                B[n] = *(const bf16x8_t*)(vT +
                    (size_t)(wc * 128 + n * 16 + lrow) * MSAMP + jb * 128 + kb2 + lk);
#pragma unroll
            for (int m = 0; m < 4; m++)
#pragma unroll
                for (int n = 0; n < 8; n++)
                    racc[m][n] = __builtin_amdgcn_mfma_f32_16x16x32_bf16(
                        A[m], B[n], racc[m][n], 0, 0, 0);
        }
        __syncthreads();
    }

    // ---- phase 3: epilogue, f32 res -> LDS, coalesced f32 [res|feat] store ----
    float* rlds = (float*)smem;   // qlds/wlds dead now (final barrier above)
#pragma unroll
    for (int m = 0; m < 4; m++)
#pragma unroll
        for (int n = 0; n < 8; n++)
#pragma unroll
            for (int r = 0; r < 4; r++)
                rlds[(wr * 64 + m * 16 + crow + r) * RS + wc * 128 + n * 16 + lrow] =
                    racc[m][n][r];
    __syncthreads();

#pragma unroll
    for (int base = 0; base < 128; base += 4) {
        int row = base + wid;
        f32x4_t a = *(const f32x4_t*)(rlds + row * RS + ln * 4);
        f32x4_t b = *(const f32x4_t*)(feat + (size_t)(r0 + row) * DMODEL + ln * 4);
        *(f32x4_t*)(out + (size_t)(r0 + row) * 512 + ln * 4)       = a;
        *(f32x4_t*)(out + (size_t)(r0 + row) * 512 + 256 + ln * 4) = b;
    }
}

// ---------------------------------------------------------------------------
extern "C" void kernel_launch(void* const* d_in, const int* in_sizes, int n_in,
                              void* d_out, int out_size, void* d_ws, size_t ws_size,
                              hipStream_t stream) {
    const float* p_xyz = (const float*)d_in[0];
    const float* feat  = (const float*)d_in[1];
    const float* Wq    = (const float*)d_in[2];
    const float* bq    = (const float*)d_in[3];
    const float* Wk    = (const float*)d_in[4];
    const float* bk    = (const float*)d_in[5];
    const float* Wv    = (const float*)d_in[6];
    const float* bv    = (const float*)d_in[7];
    float* out = (float*)d_out;

    char* ws = (char*)d_ws;
    unsigned long long* slots = (unsigned long long*)ws;                //  16 KB [2][NW][SLW]
    int*                idx   = (int*)(ws + 16384);                     //   4 KB
    unsigned short*     k_s   = (unsigned short*)(ws + 32768);          // 512 KB
    unsigned short*     vT    = (unsigned short*)(ws + 32768 + 524288); // 512 KB

    hipMemsetAsync(d_ws, 0, 16384, stream);   // invalidate slots every call

    hipLaunchKernelGGL(fps_kernel, dim3(NW), dim3(64), 0, stream,
                       p_xyz, slots, idx);
    hipLaunchKernelGGL(kv_kernel, dim3(MSAMP / 4), dim3(256), 0, stream,
                       feat, Wk, bk, Wv, bv, idx, k_s, vT);
    hipFuncSetAttribute((const void*)main_kernel,
                        hipFuncAttributeMaxDynamicSharedMemorySize, MAIN_LDS);
    hipLaunchKernelGGL(main_kernel, dim3(N_PTS / 128), dim3(256), MAIN_LDS, stream,
                       feat, Wq, bq, k_s, vT, out);
}